// Round 3
// baseline (1316.973 us; speedup 1.0000x reference)
//
#include <hip/hip_runtime.h>

#define NF0 300
#define F1 128
#define F2 64

// ---------------- CSR build ----------------

__global__ void hist_k(const int* __restrict__ dst, int* __restrict__ cnt, int E) {
    int i = blockIdx.x * blockDim.x + threadIdx.x;
    int stride = gridDim.x * blockDim.x;
    for (; i < E; i += stride) atomicAdd(&cnt[dst[i]], 1);
}

__global__ __launch_bounds__(1024) void scanA_k(const int* __restrict__ cnt, int* __restrict__ offs,
                                                int* __restrict__ partials, int n) {
    __shared__ int s[1024];
    int i = blockIdx.x * 1024 + threadIdx.x;
    int v = (i < n) ? cnt[i] : 0;
    s[threadIdx.x] = v;
    __syncthreads();
    for (int d = 1; d < 1024; d <<= 1) {
        int t = (threadIdx.x >= (unsigned)d) ? s[threadIdx.x - d] : 0;
        __syncthreads();
        s[threadIdx.x] += t;
        __syncthreads();
    }
    if (i < n) offs[i] = s[threadIdx.x] - v;  // exclusive within chunk
    if (threadIdx.x == 1023) partials[blockIdx.x] = s[1023];
}

__global__ __launch_bounds__(128) void scanB_k(int* __restrict__ partials, int nchunks) {
    __shared__ int s[128];
    int v = (threadIdx.x < nchunks) ? partials[threadIdx.x] : 0;
    s[threadIdx.x] = v;
    __syncthreads();
    for (int d = 1; d < 128; d <<= 1) {
        int t = (threadIdx.x >= (unsigned)d) ? s[threadIdx.x - d] : 0;
        __syncthreads();
        s[threadIdx.x] += t;
        __syncthreads();
    }
    if (threadIdx.x < nchunks) partials[threadIdx.x] = s[threadIdx.x] - v;  // exclusive
}

__global__ void scanC_k(int* __restrict__ offs, const int* __restrict__ partials, int* __restrict__ cursor,
                        const int* __restrict__ cnt, float* __restrict__ dinv, int n, int E) {
    int i = blockIdx.x * blockDim.x + threadIdx.x;
    if (i < n) {
        int o = offs[i] + partials[i >> 10];
        offs[i] = o;
        cursor[i] = o;
        dinv[i] = rsqrtf((float)cnt[i] + 1.0f);  // +1 self-loop; deg>=1 always
    }
    if (i == 0) offs[n] = E;
}

__global__ void fill_k(const int* __restrict__ src, const int* __restrict__ dst, int* __restrict__ cursor,
                       int* __restrict__ slots, int E) {
    int i = blockIdx.x * blockDim.x + threadIdx.x;
    int stride = gridDim.x * blockDim.x;
    for (; i < E; i += stride) {
        int d = dst[i];
        int p = atomicAdd(&cursor[d], 1);
        slots[p] = src[i];
    }
}

// ---------------- GEMM1: col-split halves, transposed-W LDS, b128 reads ----------------
// Block = 1024 thr, handles 64 output cols (half = blockIdx&1). LDS 76.8 KB -> 2 blocks/CU
// = 32 waves/CU. Wave = 8 rows; lane = col. Per 4-k: 1 ds_read_b128 + 8 s_load_dwordx4 + 32 FMA.
__global__ __launch_bounds__(1024, 8) void gemm1_k(const float* __restrict__ x, const float* __restrict__ W1,
                                                   const float* __restrict__ dinv, float* __restrict__ y1, int n) {
    __shared__ float Wt[64 * NF0];  // [c][k], stride 300 words = 75 (odd) 16B groups -> b128 conflict-free
    int half = blockIdx.x & 1;
    for (int i = threadIdx.x; i < NF0 * 64; i += 1024) {
        int k = i >> 6, c = i & 63;
        Wt[c * NF0 + k] = W1[k * F1 + half * 64 + c];  // coalesced read
    }
    __syncthreads();
    int lane = threadIdx.x & 63;
    int wwid = threadIdx.x >> 6;
    int g = (blockIdx.x >> 1) * 16 + wwid;
    int ngroups = (n + 7) >> 3;
    if (g >= ngroups) return;
    int r0 = __builtin_amdgcn_readfirstlane(g << 3);
    const float* wrow = &Wt[lane * NF0];
    int cbase = half * 64 + lane;
    if (r0 + 7 < n) {
        const float* xp = x + (size_t)r0 * NF0;
        float acc[8] = {0.f, 0.f, 0.f, 0.f, 0.f, 0.f, 0.f, 0.f};
        for (int k4 = 0; k4 < NF0; k4 += 4) {
            float4 w = *(const float4*)(wrow + k4);
#pragma unroll
            for (int r = 0; r < 8; ++r) {
                float4 xv = *(const float4*)(xp + r * NF0 + k4);  // wave-uniform -> s_load_dwordx4
                acc[r] = fmaf(xv.x, w.x, acc[r]);
                acc[r] = fmaf(xv.y, w.y, acc[r]);
                acc[r] = fmaf(xv.z, w.z, acc[r]);
                acc[r] = fmaf(xv.w, w.w, acc[r]);
            }
        }
#pragma unroll
        for (int r = 0; r < 8; ++r)
            y1[(size_t)(r0 + r) * F1 + cbase] = acc[r] * dinv[r0 + r];
    } else {  // tail
        for (int r = r0; r < n; ++r) {
            const float* xr = x + (size_t)r * NF0;
            float a = 0.f;
            for (int k = 0; k < NF0; ++k) a = fmaf(xr[k], wrow[k], a);
            y1[(size_t)r * F1 + cbase] = a * dinv[r];
        }
    }
}

// ---------------- GEMM2: transposed-W LDS (pad 132), b128 reads ----------------
// Block = 512 thr; LDS 33 KB -> 4 blocks/CU = 32 waves/CU. Wave = 8 rows; lane = col.
__global__ __launch_bounds__(512, 8) void gemm2_k(const float* __restrict__ h, const float* __restrict__ W2,
                                                  const float* __restrict__ dinv, float* __restrict__ y2, int n) {
    __shared__ float Wt[64 * 132];  // stride 132 words = 33 (odd) groups -> conflict-free
    for (int i = threadIdx.x; i < F1 * F2; i += 512) {
        int k = i >> 6, c = i & 63;
        Wt[c * 132 + k] = W2[k * F2 + c];
    }
    __syncthreads();
    int lane = threadIdx.x & 63;
    int wwid = threadIdx.x >> 6;
    int g = blockIdx.x * 8 + wwid;
    int ngroups = (n + 7) >> 3;
    if (g >= ngroups) return;
    int r0 = __builtin_amdgcn_readfirstlane(g << 3);
    const float* wrow = &Wt[lane * 132];
    if (r0 + 7 < n) {
        const float* hp = h + (size_t)r0 * F1;
        float acc[8] = {0.f, 0.f, 0.f, 0.f, 0.f, 0.f, 0.f, 0.f};
        for (int k4 = 0; k4 < F1; k4 += 4) {
            float4 w = *(const float4*)(wrow + k4);
#pragma unroll
            for (int r = 0; r < 8; ++r) {
                float4 hv = *(const float4*)(hp + r * F1 + k4);  // s_load_dwordx4
                acc[r] = fmaf(hv.x, w.x, acc[r]);
                acc[r] = fmaf(hv.y, w.y, acc[r]);
                acc[r] = fmaf(hv.z, w.z, acc[r]);
                acc[r] = fmaf(hv.w, w.w, acc[r]);
            }
        }
#pragma unroll
        for (int r = 0; r < 8; ++r)
            y2[(size_t)(r0 + r) * F2 + lane] = acc[r] * dinv[r0 + r];
    } else {
        for (int r = r0; r < n; ++r) {
            const float* hr = h + (size_t)r * F1;
            float a = 0.f;
            for (int k = 0; k < F1; ++k) a = fmaf(hr[k], wrow[k], a);
            y2[(size_t)r * F2 + lane] = a * dinv[r];
        }
    }
}

// ---------------- Pull aggregation (CSR; wave-per-node; 8 gathers in flight) ----------------

__global__ __launch_bounds__(256) void agg1_k(const float* __restrict__ y1, const int* __restrict__ offs,
                                              const int* __restrict__ slots, const float* __restrict__ dinv,
                                              const float* __restrict__ b1, float* __restrict__ hrelu, int n) {
    int gtid = blockIdx.x * 256 + threadIdx.x;
    int wid = gtid >> 6, lane = threadIdx.x & 63;
    int nw = (gridDim.x * 256) >> 6;
    int c = lane * 2;
    for (int i = wid; i < n; i += nw) {
        int row = __builtin_amdgcn_readfirstlane(i);
        int beg = offs[row], end = offs[row + 1];
        float2 acc = *(const float2*)(y1 + (size_t)row * F1 + c);  // self-loop term
        int j = beg;
        while (j < end) {
            int m = min(64, end - j);
            int sv = (lane < m) ? slots[j + lane] : 0;
            int t = 0;
            for (; t + 8 <= m; t += 8) {  // 8 gathers in flight
                float2 v0 = *(const float2*)(y1 + (size_t)__shfl(sv, t) * F1 + c);
                float2 v1 = *(const float2*)(y1 + (size_t)__shfl(sv, t + 1) * F1 + c);
                float2 v2 = *(const float2*)(y1 + (size_t)__shfl(sv, t + 2) * F1 + c);
                float2 v3 = *(const float2*)(y1 + (size_t)__shfl(sv, t + 3) * F1 + c);
                float2 v4 = *(const float2*)(y1 + (size_t)__shfl(sv, t + 4) * F1 + c);
                float2 v5 = *(const float2*)(y1 + (size_t)__shfl(sv, t + 5) * F1 + c);
                float2 v6 = *(const float2*)(y1 + (size_t)__shfl(sv, t + 6) * F1 + c);
                float2 v7 = *(const float2*)(y1 + (size_t)__shfl(sv, t + 7) * F1 + c);
                acc.x += ((v0.x + v1.x) + (v2.x + v3.x)) + ((v4.x + v5.x) + (v6.x + v7.x));
                acc.y += ((v0.y + v1.y) + (v2.y + v3.y)) + ((v4.y + v5.y) + (v6.y + v7.y));
            }
            for (; t < m; ++t) {
                float2 v = *(const float2*)(y1 + (size_t)__shfl(sv, t) * F1 + c);
                acc.x += v.x;
                acc.y += v.y;
            }
            j += m;
        }
        float dv = dinv[row];
        float2 bb = *(const float2*)(b1 + c);
        float2 hv;
        hv.x = fmaxf(fmaf(acc.x, dv, bb.x), 0.f);
        hv.y = fmaxf(fmaf(acc.y, dv, bb.y), 0.f);
        *(float2*)(hrelu + (size_t)row * F1 + c) = hv;
    }
}

__global__ __launch_bounds__(256) void agg2_k(const float* __restrict__ y2, const int* __restrict__ offs,
                                              const int* __restrict__ slots, const float* __restrict__ dinv,
                                              const float* __restrict__ b2, float* __restrict__ out, int n) {
    int gtid = blockIdx.x * 256 + threadIdx.x;
    int wid = gtid >> 6, lane = threadIdx.x & 63;
    int nw = (gridDim.x * 256) >> 6;
    for (int i = wid; i < n; i += nw) {
        int row = __builtin_amdgcn_readfirstlane(i);
        int beg = offs[row], end = offs[row + 1];
        float acc = y2[(size_t)row * F2 + lane];  // self-loop term
        int j = beg;
        while (j < end) {
            int m = min(64, end - j);
            int sv = (lane < m) ? slots[j + lane] : 0;
            int t = 0;
            for (; t + 8 <= m; t += 8) {
                float v0 = y2[(size_t)__shfl(sv, t) * F2 + lane];
                float v1 = y2[(size_t)__shfl(sv, t + 1) * F2 + lane];
                float v2 = y2[(size_t)__shfl(sv, t + 2) * F2 + lane];
                float v3 = y2[(size_t)__shfl(sv, t + 3) * F2 + lane];
                float v4 = y2[(size_t)__shfl(sv, t + 4) * F2 + lane];
                float v5 = y2[(size_t)__shfl(sv, t + 5) * F2 + lane];
                float v6 = y2[(size_t)__shfl(sv, t + 6) * F2 + lane];
                float v7 = y2[(size_t)__shfl(sv, t + 7) * F2 + lane];
                acc += ((v0 + v1) + (v2 + v3)) + ((v4 + v5) + (v6 + v7));
            }
            for (; t < m; ++t) acc += y2[(size_t)__shfl(sv, t) * F2 + lane];
            j += m;
        }
        out[(size_t)row * F2 + lane] = fmaf(acc, dinv[row], b2[lane]);
    }
}

// ---------------- launch ----------------

extern "C" void kernel_launch(void* const* d_in, const int* in_sizes, int n_in,
                              void* d_out, int out_size, void* d_ws, size_t ws_size,
                              hipStream_t stream) {
    const float* x  = (const float*)d_in[0];
    const int*   ei = (const int*)d_in[1];
    const float* W1 = (const float*)d_in[2];
    const float* b1 = (const float*)d_in[3];
    const float* W2 = (const float*)d_in[4];
    const float* b2 = (const float*)d_in[5];
    float* out = (float*)d_out;

    int n = in_sizes[0] / NF0;
    int E = in_sizes[1] / 2;
    const int* srcv = ei;      // edge_index[0]
    const int* dstv = ei + E;  // edge_index[1]

    char* ws = (char*)d_ws;
    size_t off = 0;
    auto alloc = [&](size_t bytes) -> void* {
        void* p = ws + off;
        off = (off + bytes + 255) & ~(size_t)255;
        return p;
    };
    float* dinv   = (float*)alloc((size_t)n * 4);
    int* cnt      = (int*)alloc((size_t)n * 4);
    int* offs     = (int*)alloc((size_t)(n + 1) * 4);
    int* cursor   = (int*)alloc((size_t)n * 4);
    int* partials = (int*)alloc(((size_t)(n + 1023) / 1024) * 4);
    int* slots    = (int*)alloc((size_t)E * 4);
    float* y1     = (float*)alloc((size_t)n * F1 * 4);
    float* hrelu  = (float*)alloc((size_t)n * F1 * 4);
    float* y2     = y1;  // y1 dead after agg1; reuse

    int nchunks = (n + 1023) / 1024;

    hipMemsetAsync(cnt, 0, (size_t)n * 4, stream);
    hist_k<<<4096, 256, 0, stream>>>(dstv, cnt, E);
    scanA_k<<<nchunks, 1024, 0, stream>>>(cnt, offs, partials, n);
    scanB_k<<<1, 128, 0, stream>>>(partials, nchunks);
    scanC_k<<<(n + 255) / 256, 256, 0, stream>>>(offs, partials, cursor, cnt, dinv, n, E);
    fill_k<<<4096, 256, 0, stream>>>(srcv, dstv, cursor, slots, E);

    int ngroups = (n + 7) >> 3;                     // 8 rows per wave
    int g1_blocks = 2 * ((ngroups + 15) / 16);      // ×2 col-halves, 16 waves/block
    int g2_blocks = (ngroups + 7) / 8;              // 8 waves/block
    gemm1_k<<<g1_blocks, 1024, 0, stream>>>(x, W1, dinv, y1, n);
    agg1_k<<<2048, 256, 0, stream>>>(y1, offs, slots, dinv, b1, hrelu, n);
    gemm2_k<<<g2_blocks, 512, 0, stream>>>(hrelu, W2, dinv, y2, n);
    agg2_k<<<2048, 256, 0, stream>>>(y2, offs, slots, dinv, b2, out, n);
}